// Round 11
// baseline (2131.602 us; speedup 1.0000x reference)
//
#include <hip/hip_runtime.h>
#include <stdint.h>

// Problem constants (ComplexChebTemporalConv)
#define Bn 4
#define Nn 2048
#define Tn 64
#define CIn 32
#define COn 32
#define Kn 6
#define TAUn 3
#define Jn 8192  // B*T*CI

typedef _Float16 f16;
typedef _Float16 f16x2 __attribute__((ext_vector_type(2)));
typedef _Float16 f16x4 __attribute__((ext_vector_type(4)));
typedef _Float16 f16x8 __attribute__((ext_vector_type(8)));
typedef float f32x4 __attribute__((ext_vector_type(4)));

template <int N> struct ic { static constexpr int v = N; };

#if defined(__has_builtin)
#if __has_builtin(__builtin_amdgcn_fdot2)
#define HAVE_FDOT2 1
#endif
#endif

__device__ __forceinline__ float fdot2(f16x2 a, f16x2 b, float c) {
#ifdef HAVE_FDOT2
  return __builtin_amdgcn_fdot2(a, b, c, false);
#else
  return c + (float)a[0] * (float)b[0] + (float)a[1] * (float)b[1];
#endif
}

__device__ __forceinline__ void gld_lds16(const void* g, void* l) {
  auto gp = (const __attribute__((address_space(1))) uint32_t*)(uintptr_t)g;
  auto lp = (__attribute__((address_space(3))) uint32_t*)(uint32_t)(uintptr_t)l;
  __builtin_amdgcn_global_load_lds(gp, lp, 16, 0, 0);
}

// ---------------------------------------------------------------------------
// pack_gso: fp32 gso planes -> f16 planes (row-major [n][m])
// ---------------------------------------------------------------------------
__global__ __launch_bounds__(256) void pack_gso(const float* __restrict__ gr,
                                                const float* __restrict__ gi,
                                                f16* __restrict__ Gr,
                                                f16* __restrict__ Gi) {
  int u = blockIdx.x * 256 + threadIdx.x;
  float4 vr = ((const float4*)gr)[u];
  float4 vi = ((const float4*)gi)[u];
  f16x4 hr, hi;
  hr[0] = (f16)vr.x; hr[1] = (f16)vr.y; hr[2] = (f16)vr.z; hr[3] = (f16)vr.w;
  hi[0] = (f16)vi.x; hi[1] = (f16)vi.y; hi[2] = (f16)vi.z; hi[3] = (f16)vi.w;
  ((f16x4*)Gr)[u] = hr;
  ((f16x4*)Gi)[u] = hi;
}

// ---------------------------------------------------------------------------
// pack_x: x [b][n][q] fp32 -> combined P0[j=b*2048+q][4096]: re at col n, im at 2048+n
// ---------------------------------------------------------------------------
__global__ __launch_bounds__(256) void pack_x(const float* __restrict__ xr,
                                              const float* __restrict__ xi,
                                              f16* __restrict__ P0) {
  __shared__ float tile[64][65];
  const int t = threadIdx.x;
  const int q0 = blockIdx.x * 64;
  const int n0 = blockIdx.y * 64;
  const int b = blockIdx.z;
  const int rr = t >> 4;
  const int cc = (t & 15) * 4;
  #pragma unroll
  for (int plane = 0; plane < 2; ++plane) {
    const float* src = plane ? xi : xr;
    if (plane) __syncthreads();
    #pragma unroll
    for (int it = 0; it < 4; ++it) {
      int n = it * 16 + rr;
      float4 v = *(const float4*)(src + ((size_t)b * Nn + n0 + n) * 2048 + q0 + cc);
      tile[n][cc + 0] = v.x; tile[n][cc + 1] = v.y;
      tile[n][cc + 2] = v.z; tile[n][cc + 3] = v.w;
    }
    __syncthreads();
    #pragma unroll
    for (int it = 0; it < 4; ++it) {
      int q = it * 16 + rr;
      f16x4 hv;
      hv[0] = (f16)tile[cc + 0][q];
      hv[1] = (f16)tile[cc + 1][q];
      hv[2] = (f16)tile[cc + 2][q];
      hv[3] = (f16)tile[cc + 3][q];
      *(f16x4*)(P0 + ((size_t)b * 2048 + q0 + q) * 4096 + plane * 2048 + n0 + cc) = hv;
    }
  }
}

// ---------------------------------------------------------------------------
// pack_w: wpk[idx].x = (wr, -wi), wpk[idx].y = (wi, wr); idx = [k][tau][ci][co]
// ---------------------------------------------------------------------------
__global__ __launch_bounds__(256) void pack_w(const float* __restrict__ wr,
                                              const float* __restrict__ wi,
                                              uint2* __restrict__ wpk) {
  int idx = blockIdx.x * 256 + threadIdx.x;
  if (idx >= Kn * TAUn * CIn * COn) return;
  float r = wr[idx], i = wi[idx];
  uint16_t hr = __builtin_bit_cast(uint16_t, (f16)r);
  uint16_t hi = __builtin_bit_cast(uint16_t, (f16)i);
  uint16_t hni = __builtin_bit_cast(uint16_t, (f16)(-i));
  uint2 o;
  o.x = (uint32_t)hr | ((uint32_t)hni << 16);
  o.y = (uint32_t)hi | ((uint32_t)hr << 16);
  wpk[idx] = o;
}

// ---------------------------------------------------------------------------
// cheb_gemm r11: r10 schedule HALVED for 2 blocks/CU (block-level TLP).
//   256 thr = 4 waves (2M x 2N); tile 128(n') x 128(j), BK=64, wave 64x64.
//   LDS 64 KB: 8 x 8KB chunks (A0,A1,B0,B1 per parity E). 2 blocks/CU ->
//   when block A stalls at its gate/lgkm, block B's waves feed the MFMA pipe.
// Staging is COALESCED + XOR-SWIZZLED: LDS linear (gld_lds dest = uniform +
//   lane*16); GLOBAL src carries the swizzle c_g = cl ^ (row&7) -> each
//   8-lane group reads one contiguous 128B row segment (8 L2 lines/op vs 64).
//   Frag reads un-swizzle: elem off = row*64 + ((ks*4+sub)^(rr&7))*8
//   = qX*2048 + f*1024 + rr*64 + (sub^(rr&3))*8 + (ks^(rr>>2&1))*32.
//   Bank check: 8-lane phase hits banks 4*(c^rr) (all distinct) - clean.
// Schedule per K-tile (r10-proven, 2 barriers): gate vmcnt(4)+bar;
//   P0{loadA(0),loadB0,stage A1(kt+1),mfma}; P1{loadB1,stage B1(kt+1),mfma};
//   P2{loadA(1),lgkmcnt(0)+bar,stage B0(kt+2),mfma}; P3{stage A0(kt+2),mfma}.
//   2 ops/chunk -> queue at gate(kt) identical to r10: 4 old + 4 in flight.
//   WAR: depth-2 stages (parity E slots) covered by mid-bar; depth-1 (E^1)
//   by the gate. Prologue = 6 chunks in steady-state queue order.
// XCD swizzle: bj = xcd*8 + (l>>5), bn = l&31 (2048 blocks, 64 j-panels).
//   C[n'][j] = sum G2[n'][k'] P[j][k'];  G2 = [[Gr,-Gi],[Gi,Gr]].
// MODE 0: Q = C ; MODE 1: Q = 2C - Q (in place).
// ---------------------------------------------------------------------------
template <int MODE>
__global__ __launch_bounds__(256, 2) void cheb_gemm(
    const f16* __restrict__ Gr, const f16* __restrict__ Gi,
    const f16* __restrict__ P, f16* __restrict__ Q) {
  extern __shared__ __align__(16) char lds[];
  f16* L = (f16*)lds;

  const int tid = threadIdx.x;
  const int lane = tid & 63;
  const int w = tid >> 6;
  const int wm = w >> 1;              // 0..1 : 64-row n'-strip
  const int wn = w & 1;               // 0..1 : 64-row j-strip
  const int sub = lane >> 4, rr = lane & 15;

  const int bid = blockIdx.x;
  const int xcd = bid & 7;
  const int l = bid >> 3;             // 0..255 in-XCD
  const int bj = xcd * 8 + (l >> 5);  // 0..63
  const int bn = l & 31;              // 0..31
  const int n0 = bn * 128, j0 = bj * 128;
  const bool top = n0 < 2048;
  const int gmbase = n0 & 2047;

  // ---- staging invariants (coalesced, global-side swizzle) ----
  const int trow = tid >> 3;                       // 0..31
  const int cg = (tid & 7) ^ (trow & 7);           // swizzled 16B k-chunk
  const size_t aoffg = (size_t)(gmbase + trow) * 2048 + cg * 8;
  const size_t boffg = (size_t)(j0 + trow) * 4096 + cg * 8;
  const int sdst = w * 512;                        // + p*2048 + slot*4096 (elems)

  // ---- frag-read invariants (un-swizzle) ----
  const int arb = rr * 64 + (sub ^ (rr & 3)) * 8;  // + qX*2048 + f*1024 + kofs
  const int x32 = ((rr >> 2) & 1) * 32;
  const int kofs[2] = {x32, 32 - x32};             // (ks ^ xb)*32

  auto stageA = [&](const f16* plane, int kcol, int h, int slot) {
    #pragma unroll
    for (int p = 0; p < 2; ++p)
      gld_lds16(plane + aoffg + h * 131072 + p * 65536 + kcol,
                L + slot * 4096 + sdst + p * 2048);
  };
  auto stageB = [&](int kt_, int h, int slot) {
    #pragma unroll
    for (int p = 0; p < 2; ++p)
      gld_lds16(P + boffg + h * 262144 + p * 131072 + kt_ * 64,
                L + slot * 4096 + sdst + p * 2048);
  };
  auto Aplane = [&](int kt_) -> const f16* {
    bool kr = (kt_ & 32) != 0;  // k' >= 2048
    return top ? (kr ? Gi : Gr) : (kr ? Gr : Gi);
  };

  f32x4 acc[4][4] = {};
  f16x8 afr[2][2], bfr0[2][2], bfr1[2][2];

  // prologue: 6 chunks in steady-state queue order
  stageB(0, 0, 2);             // B0(0)
  stageA(Aplane(0), 0, 0, 0);  // A0(0)
  stageA(Aplane(0), 0, 1, 1);  // A1(0)
  stageB(0, 1, 3);             // B1(0)
  stageB(1, 0, 6);             // B0(1)
  stageA(Aplane(1), 64, 0, 4); // A0(1)

  for (int k2 = 0; k2 < 32; ++k2) {
    const int ktb = k2 * 2;

    auto tile = [&](auto ec) {
      constexpr int E = decltype(ec)::v;
      const int kt = ktb + E;
      const int ktn = (kt + 1) & 63;    // wrap -> dummy restage, uniform counts
      const int ktn2 = (kt + 2) & 63;
      const f16* apn = Aplane(ktn);
      const f16* apn2 = Aplane(ktn2);
      const int kcoln = (ktn * 64) & 2047;
      const int kcoln2 = (ktn2 * 64) & 2047;
      const bool negA = top && (kt & 32);

      auto loadA = [&](int qm) {
        #pragma unroll
        for (int f = 0; f < 2; ++f)
          #pragma unroll
          for (int ks = 0; ks < 2; ++ks)
            afr[f][ks] = *(const f16x8*)(
                L + (E * 4 + wm) * 4096 + qm * 2048 + f * 1024 + arb + kofs[ks]);
        if (negA) {
          #pragma unroll
          for (int f = 0; f < 2; ++f) { afr[f][0] = -afr[f][0]; afr[f][1] = -afr[f][1]; }
        }
      };
      auto loadB = [&](f16x8 (&bq)[2][2], int qn) {
        #pragma unroll
        for (int fc = 0; fc < 2; ++fc)
          #pragma unroll
          for (int ks = 0; ks < 2; ++ks)
            bq[fc][ks] = *(const f16x8*)(
                L + (E * 4 + 2 + wn) * 4096 + qn * 2048 + fc * 1024 + arb + kofs[ks]);
      };
      auto mf16 = [&](f16x8 (&bq)[2][2], int accR, int accC) {
        __builtin_amdgcn_s_setprio(1);
        #pragma unroll
        for (int ks = 0; ks < 2; ++ks)     // ks OUTER: 4 independent per pass
          #pragma unroll
          for (int f = 0; f < 2; ++f)
            #pragma unroll
            for (int fc = 0; fc < 2; ++fc)
              acc[accR + f][accC + fc] = __builtin_amdgcn_mfma_f32_16x16x32_f16(
                  afr[f][ks], bq[fc][ks], acc[accR + f][accC + fc], 0, 0, 0);
        __builtin_amdgcn_s_setprio(0);
      };

      // gate: tile kt's 4 chunks visible; B0/A0(kt+1) stay in flight
      asm volatile("s_waitcnt vmcnt(4)" ::: "memory");
      __builtin_amdgcn_s_barrier();

      // P0: quadrant (0,0)
      loadA(0); loadB(bfr0, 0);
      stageA(apn, kcoln, 1, (E ^ 1) * 4 + 1);
      mf16(bfr0, 0, 0);

      // P1: quadrant (0,1)
      loadB(bfr1, 1);
      stageB(ktn, 1, (E ^ 1) * 4 + 3);
      mf16(bfr1, 0, 2);

      // P2: quadrant (1,1) -- mid-bar between ds-reads and depth-2 stages
      loadA(1);
      asm volatile("s_waitcnt lgkmcnt(0)" ::: "memory");
      __builtin_amdgcn_s_barrier();
      stageB(ktn2, 0, E * 4 + 2);
      mf16(bfr1, 2, 2);

      // P3: quadrant (1,0)
      stageA(apn2, kcoln2, 0, E * 4 + 0);
      mf16(bfr0, 2, 0);
    };

    tile(ic<0>{});
    tile(ic<1>{});
  }

  asm volatile("s_waitcnt vmcnt(0)" ::: "memory");

  // Epilogue: transposed write Q[j][n']; C/D map col=lane&15, row=(lane>>4)*4+r
  #pragma unroll
  for (int fc = 0; fc < 4; ++fc) {
    size_t j = (size_t)j0 + wn * 64 + fc * 16 + (lane & 15);
    #pragma unroll
    for (int fr = 0; fr < 4; ++fr) {
      int nn = n0 + wm * 64 + fr * 16 + ((lane >> 4) << 2);
      size_t off = j * 4096 + nn;
      f16x4 v;
      if (MODE == 1) {
        f16x4 o = *(const f16x4*)(Q + off);
        #pragma unroll
        for (int r = 0; r < 4; ++r)
          v[r] = (f16)(2.0f * acc[fr][fc][r] - (float)o[r]);
      } else {
        #pragma unroll
        for (int r = 0; r < 4; ++r)
          v[r] = (f16)acc[fr][fc][r];
      }
      *(f16x4*)(Q + off) = v;
    }
  }
}

// ---------------------------------------------------------------------------
// contract_k: out[b][n][t][o] (+)= sum_{tau,i} Re/Im( P_k[b,n,t-tau,i]*w[k,tau,i,o] )
// P combined plane: re at [j][n], im at [j][2048+n], row stride 4096.
// ---------------------------------------------------------------------------
template <bool CPLX>
__global__ __launch_bounds__(256, 4) void contract_k(
    const f16* __restrict__ Pc, const uint2* __restrict__ wpk,
    const float* __restrict__ biasr, const float* __restrict__ biasi,
    float* __restrict__ out, int k) {
  __shared__ __align__(16) uint32_t Plds[96 * 64];
  __shared__ __align__(16) uint32_t WA[96 * 32];
  __shared__ __align__(16) uint32_t WB[CPLX ? 96 * 32 : 32];

  const int t = threadIdx.x;
  const int n0 = blockIdx.x * 64;
  const int tt = blockIdx.y;
  const int b = blockIdx.z;

  #pragma unroll
  for (int it = 0; it < 3; ++it) {
    int task = it * 256 + t;
    int row = task >> 3, oc = task & 7;
    int tp = (tt - 2) * 32 + row;
    uint4 ur = {0, 0, 0, 0}, ui = {0, 0, 0, 0};
    if (tp >= 0) {
      size_t goff = ((size_t)b * 2048 + tp) * 4096 + n0 + oc * 8;
      ur = *(const uint4*)(Pc + goff);
      ui = *(const uint4*)(Pc + goff + 2048);
    }
    uint32_t* dst = &Plds[row * 64 + oc * 8];
    dst[0] = (ur.x & 0xffffu) | (ui.x << 16);
    dst[1] = (ur.x >> 16) | (ui.x & 0xffff0000u);
    dst[2] = (ur.y & 0xffffu) | (ui.y << 16);
    dst[3] = (ur.y >> 16) | (ui.y & 0xffff0000u);
    dst[4] = (ur.z & 0xffffu) | (ui.z << 16);
    dst[5] = (ur.z >> 16) | (ui.z & 0xffff0000u);
    dst[6] = (ur.w & 0xffffu) | (ui.w << 16);
    dst[7] = (ur.w >> 16) | (ui.w & 0xffff0000u);
  }
  #pragma unroll
  for (int it = 0; it < 12; ++it) {
    int idx = it * 256 + t;
    int q = idx >> 5, o = idx & 31;
    int tau = 2 - (q >> 5), ci = q & 31;
    uint2 wv = wpk[((k * TAUn + tau) * CIn + ci) * COn + o];
    WA[idx] = wv.x;
    if (CPLX) WB[idx] = wv.y;
  }
  __syncthreads();

  const int no = t & 7, ng = t >> 3;
  float aR[8] = {0, 0, 0, 0, 0, 0, 0, 0};
  float aI[8] = {0, 0, 0, 0, 0, 0, 0, 0};
  for (int q = 0; q < 96; ++q) {
    uint2 pp = *(const uint2*)&Plds[q * 64 + ng * 2];
    f16x2 h0 = __builtin_bit_cast(f16x2, pp.x);
    f16x2 h1 = __builtin_bit_cast(f16x2, pp.y);
    uint4 wa = *(const uint4*)&WA[q * 32 + no * 4];
    const uint32_t* wap = &wa.x;
    #pragma unroll
    for (int c = 0; c < 4; ++c) {
      f16x2 wv = __builtin_bit_cast(f16x2, wap[c]);
      aR[c] = fdot2(h0, wv, aR[c]);
      aR[4 + c] = fdot2(h1, wv, aR[4 + c]);
    }
    if (CPLX) {
      uint4 wb = *(const uint4*)&WB[q * 32 + no * 4];
      const uint32_t* wbp = &wb.x;
      #pragma unroll
      for (int c = 0; c < 4; ++c) {
        f16x2 wv = __builtin_bit_cast(f16x2, wbp[c]);
        aI[c] = fdot2(h0, wv, aI[c]);
        aI[4 + c] = fdot2(h1, wv, aI[4 + c]);
      }
    }
  }

  #pragma unroll
  for (int a = 0; a < 2; ++a) {
    size_t n = (size_t)n0 + ng * 2 + a;
    size_t ob = (((size_t)b * Nn + n) * Tn + tt) * COn + no * 4;
    if (!CPLX) {
      float4 v;
      v.x = aR[a * 4 + 0]; v.y = aR[a * 4 + 1];
      v.z = aR[a * 4 + 2]; v.w = aR[a * 4 + 3];
      float4 cur;
      if (k == 0) cur = *(const float4*)(biasr + no * 4);
      else cur = *(const float4*)(out + ob);
      v.x += cur.x; v.y += cur.y; v.z += cur.z; v.w += cur.w;
      *(float4*)(out + ob) = v;
    } else {
      float* po = out + ob * 2;
      float4 lo, hi;
      lo.x = aR[a * 4 + 0]; lo.y = aI[a * 4 + 0];
      lo.z = aR[a * 4 + 1]; lo.w = aI[a * 4 + 1];
      hi.x = aR[a * 4 + 2]; hi.y = aI[a * 4 + 2];
      hi.z = aR[a * 4 + 3]; hi.w = aI[a * 4 + 3];
      float4 c0, c1;
      if (k == 0) {
        const float* pr = biasr + no * 4;
        const float* pi = biasi + no * 4;
        c0 = make_float4(pr[0], pi[0], pr[1], pi[1]);
        c1 = make_float4(pr[2], pi[2], pr[3], pi[3]);
      } else {
        c0 = *(const float4*)(po);
        c1 = *(const float4*)(po + 4);
      }
      lo.x += c0.x; lo.y += c0.y; lo.z += c0.z; lo.w += c0.w;
      hi.x += c1.x; hi.y += c1.y; hi.z += c1.z; hi.w += c1.w;
      *(float4*)(po) = lo;
      *(float4*)(po + 4) = hi;
    }
  }
}

// ---------------------------------------------------------------------------
extern "C" void kernel_launch(void* const* d_in, const int* in_sizes, int n_in,
                              void* d_out, int out_size, void* d_ws, size_t ws_size,
                              hipStream_t stream) {
  (void)in_sizes; (void)n_in;
  const float* xr = (const float*)d_in[0];
  const float* xi = (const float*)d_in[1];
  const float* gr = (const float*)d_in[2];
  const float* gi = (const float*)d_in[3];
  const float* wr = (const float*)d_in[4];
  const float* wi = (const float*)d_in[5];
  const float* biasr = (const float*)d_in[6];
  const float* biasi = (const float*)d_in[7];
  float* out = (float*)d_out;

  const size_t PPLANE = (size_t)Jn * 4096 * sizeof(f16);  // 67,108,864 (combined)
  const size_t GPLANE = (size_t)Nn * Nn * sizeof(f16);    // 8,388,608
  const size_t WPK = (size_t)Kn * TAUn * CIn * COn * 8;   // 147,456
  if (ws_size < 2 * PPLANE + 2 * GPLANE + WPK) return;

  char* ws = (char*)d_ws;
  f16* P0 = (f16*)(ws);
  f16* P1 = (f16*)(ws + PPLANE);
  f16* Gr = (f16*)(ws + 2 * PPLANE);
  f16* Gi = (f16*)(ws + 2 * PPLANE + GPLANE);
  uint2* wpk = (uint2*)(ws + 2 * PPLANE + 2 * GPLANE);

  const bool cplx = (out_size == 2 * Bn * Nn * Tn * COn);

  pack_gso<<<dim3(4096), dim3(256), 0, stream>>>(gr, gi, Gr, Gi);
  pack_x<<<dim3(32, 32, 4), dim3(256), 0, stream>>>(xr, xi, P0);
  pack_w<<<dim3(72), dim3(256), 0, stream>>>(wr, wi, wpk);

  #define CONTRACT(KK, Pp)                                                         \
    do {                                                                           \
      if (cplx)                                                                    \
        contract_k<true><<<dim3(32, 64, 4), dim3(256), 0, stream>>>(               \
            Pp, wpk, biasr, biasi, out, KK);                                       \
      else                                                                         \
        contract_k<false><<<dim3(32, 64, 4), dim3(256), 0, stream>>>(              \
            Pp, wpk, biasr, biasi, out, KK);                                       \
    } while (0)

  CONTRACT(0, P0);
  cheb_gemm<0><<<dim3(2048), dim3(256), 65536, stream>>>(Gr, Gi, P0, P1);
  CONTRACT(1, P1);
  cheb_gemm<1><<<dim3(2048), dim3(256), 65536, stream>>>(Gr, Gi, P1, P0);
  CONTRACT(2, P0);
  cheb_gemm<1><<<dim3(2048), dim3(256), 65536, stream>>>(Gr, Gi, P0, P1);
  CONTRACT(3, P1);
  cheb_gemm<1><<<dim3(2048), dim3(256), 65536, stream>>>(Gr, Gi, P1, P0);
  CONTRACT(4, P0);
  cheb_gemm<1><<<dim3(2048), dim3(256), 65536, stream>>>(Gr, Gi, P0, P1);
  CONTRACT(5, P1);
  #undef CONTRACT
}

// Round 12
// 1940.121 us; speedup vs baseline: 1.0987x; 1.0987x over previous
//
#include <hip/hip_runtime.h>
#include <stdint.h>

// Problem constants (ComplexChebTemporalConv)
#define Bn 4
#define Nn 2048
#define Tn 64
#define CIn 32
#define COn 32
#define Kn 6
#define TAUn 3
#define Jn 8192  // B*T*CI

typedef _Float16 f16;
typedef _Float16 f16x2 __attribute__((ext_vector_type(2)));
typedef _Float16 f16x4 __attribute__((ext_vector_type(4)));
typedef _Float16 f16x8 __attribute__((ext_vector_type(8)));
typedef float f32x4 __attribute__((ext_vector_type(4)));

template <int N> struct ic { static constexpr int v = N; };

#if defined(__has_builtin)
#if __has_builtin(__builtin_amdgcn_fdot2)
#define HAVE_FDOT2 1
#endif
#endif

__device__ __forceinline__ float fdot2(f16x2 a, f16x2 b, float c) {
#ifdef HAVE_FDOT2
  return __builtin_amdgcn_fdot2(a, b, c, false);
#else
  return c + (float)a[0] * (float)b[0] + (float)a[1] * (float)b[1];
#endif
}

__device__ __forceinline__ void gld_lds16(const void* g, void* l) {
  auto gp = (const __attribute__((address_space(1))) uint32_t*)(uintptr_t)g;
  auto lp = (__attribute__((address_space(3))) uint32_t*)(uint32_t)(uintptr_t)l;
  __builtin_amdgcn_global_load_lds(gp, lp, 16, 0, 0);
}

// ---------------------------------------------------------------------------
// pack_gso: fp32 gso planes -> f16 planes (row-major [n][m])
// ---------------------------------------------------------------------------
__global__ __launch_bounds__(256) void pack_gso(const float* __restrict__ gr,
                                                const float* __restrict__ gi,
                                                f16* __restrict__ Gr,
                                                f16* __restrict__ Gi) {
  int u = blockIdx.x * 256 + threadIdx.x;
  float4 vr = ((const float4*)gr)[u];
  float4 vi = ((const float4*)gi)[u];
  f16x4 hr, hi;
  hr[0] = (f16)vr.x; hr[1] = (f16)vr.y; hr[2] = (f16)vr.z; hr[3] = (f16)vr.w;
  hi[0] = (f16)vi.x; hi[1] = (f16)vi.y; hi[2] = (f16)vi.z; hi[3] = (f16)vi.w;
  ((f16x4*)Gr)[u] = hr;
  ((f16x4*)Gi)[u] = hi;
}

// ---------------------------------------------------------------------------
// pack_x: x [b][n][q] fp32 -> combined P0[j=b*2048+q][4096]: re at col n, im at 2048+n
// ---------------------------------------------------------------------------
__global__ __launch_bounds__(256) void pack_x(const float* __restrict__ xr,
                                              const float* __restrict__ xi,
                                              f16* __restrict__ P0) {
  __shared__ float tile[64][65];
  const int t = threadIdx.x;
  const int q0 = blockIdx.x * 64;
  const int n0 = blockIdx.y * 64;
  const int b = blockIdx.z;
  const int rr = t >> 4;
  const int cc = (t & 15) * 4;
  #pragma unroll
  for (int plane = 0; plane < 2; ++plane) {
    const float* src = plane ? xi : xr;
    if (plane) __syncthreads();
    #pragma unroll
    for (int it = 0; it < 4; ++it) {
      int n = it * 16 + rr;
      float4 v = *(const float4*)(src + ((size_t)b * Nn + n0 + n) * 2048 + q0 + cc);
      tile[n][cc + 0] = v.x; tile[n][cc + 1] = v.y;
      tile[n][cc + 2] = v.z; tile[n][cc + 3] = v.w;
    }
    __syncthreads();
    #pragma unroll
    for (int it = 0; it < 4; ++it) {
      int q = it * 16 + rr;
      f16x4 hv;
      hv[0] = (f16)tile[cc + 0][q];
      hv[1] = (f16)tile[cc + 1][q];
      hv[2] = (f16)tile[cc + 2][q];
      hv[3] = (f16)tile[cc + 3][q];
      *(f16x4*)(P0 + ((size_t)b * 2048 + q0 + q) * 4096 + plane * 2048 + n0 + cc) = hv;
    }
  }
}

// ---------------------------------------------------------------------------
// pack_w: wpk[idx].x = (wr, -wi), wpk[idx].y = (wi, wr); idx = [k][tau][ci][co]
// ---------------------------------------------------------------------------
__global__ __launch_bounds__(256) void pack_w(const float* __restrict__ wr,
                                              const float* __restrict__ wi,
                                              uint2* __restrict__ wpk) {
  int idx = blockIdx.x * 256 + threadIdx.x;
  if (idx >= Kn * TAUn * CIn * COn) return;
  float r = wr[idx], i = wi[idx];
  uint16_t hr = __builtin_bit_cast(uint16_t, (f16)r);
  uint16_t hi = __builtin_bit_cast(uint16_t, (f16)i);
  uint16_t hni = __builtin_bit_cast(uint16_t, (f16)(-i));
  uint2 o;
  o.x = (uint32_t)hr | ((uint32_t)hni << 16);
  o.y = (uint32_t)hi | ((uint32_t)hr << 16);
  wpk[idx] = o;
}

// ---------------------------------------------------------------------------
// cheb_gemm r12 = r11 kernel + SQUARE co-residency swizzle.
//   256 thr = 4 waves (2M x 2N); tile 128(n') x 128(j), BK=64, wave 64x64.
//   LDS 64 KB: 8 x 8KB chunks; 2 blocks/CU (block-level TLP).
// Swizzle: the 64 co-resident blocks per XCD form an 8x8 (bn x bj) SQUARE:
//   s = l&63, wv = l>>6; bj = xcd*8 + (s>>3); bn = (s&7) + 8*wv.
//   Window panel footprint: 8 A + 8 B panels = 16 MB (r11's 2x32 rect was
//   32 A + 2 B = 34 MB -> measured 1.1 GB fill, 4 windows x 8 XCD x 34 MB).
//   Per-k-slice L2 set 256 KB -> 2x k-drift tolerance for decoupled blocks.
// Staging COALESCED + XOR-SWIZZLED (r11-proven): LDS linear; global src
//   carries swizzle cg = (tid&7)^(trow&7); frag reads un-swizzle with
//   hoisted constants. Bank-clean (verified; 0 conflicts measured).
// Schedule per K-tile (r10-proven, 2 barriers): gate vmcnt(4)+bar;
//   P0{loadA(0),loadB0,stage A1(kt+1),mfma}; P1{loadB1,stage B1(kt+1),mfma};
//   P2{loadA(1),lgkmcnt(0)+bar,stage B0(kt+2),mfma}; P3{stage A0(kt+2),mfma}.
//   C[n'][j] = sum G2[n'][k'] P[j][k'];  G2 = [[Gr,-Gi],[Gi,Gr]].
// MODE 0: Q = C ; MODE 1: Q = 2C - Q (in place).
// ---------------------------------------------------------------------------
template <int MODE>
__global__ __launch_bounds__(256, 2) void cheb_gemm(
    const f16* __restrict__ Gr, const f16* __restrict__ Gi,
    const f16* __restrict__ P, f16* __restrict__ Q) {
  extern __shared__ __align__(16) char lds[];
  f16* L = (f16*)lds;

  const int tid = threadIdx.x;
  const int lane = tid & 63;
  const int w = tid >> 6;
  const int wm = w >> 1;              // 0..1 : 64-row n'-strip
  const int wn = w & 1;               // 0..1 : 64-row j-strip
  const int sub = lane >> 4, rr = lane & 15;

  const int bid = blockIdx.x;
  const int xcd = bid & 7;
  const int l = bid >> 3;             // 0..255 in-XCD
  const int s = l & 63, wv = l >> 6;  // window pos / window idx
  const int bj = xcd * 8 + (s >> 3);  // 0..63
  const int bn = (s & 7) + 8 * wv;    // 0..31
  const int n0 = bn * 128, j0 = bj * 128;
  const bool top = n0 < 2048;
  const int gmbase = n0 & 2047;

  // ---- staging invariants (coalesced, global-side swizzle) ----
  const int trow = tid >> 3;                       // 0..31
  const int cg = (tid & 7) ^ (trow & 7);           // swizzled 16B k-chunk
  const size_t aoffg = (size_t)(gmbase + trow) * 2048 + cg * 8;
  const size_t boffg = (size_t)(j0 + trow) * 4096 + cg * 8;
  const int sdst = w * 512;                        // + p*2048 + slot*4096 (elems)

  // ---- frag-read invariants (un-swizzle) ----
  const int arb = rr * 64 + (sub ^ (rr & 3)) * 8;  // + qX*2048 + f*1024 + kofs
  const int x32 = ((rr >> 2) & 1) * 32;
  const int kofs[2] = {x32, 32 - x32};             // (ks ^ xb)*32

  auto stageA = [&](const f16* plane, int kcol, int h, int slot) {
    #pragma unroll
    for (int p = 0; p < 2; ++p)
      gld_lds16(plane + aoffg + h * 131072 + p * 65536 + kcol,
                L + slot * 4096 + sdst + p * 2048);
  };
  auto stageB = [&](int kt_, int h, int slot) {
    #pragma unroll
    for (int p = 0; p < 2; ++p)
      gld_lds16(P + boffg + h * 262144 + p * 131072 + kt_ * 64,
                L + slot * 4096 + sdst + p * 2048);
  };
  auto Aplane = [&](int kt_) -> const f16* {
    bool kr = (kt_ & 32) != 0;  // k' >= 2048
    return top ? (kr ? Gi : Gr) : (kr ? Gr : Gi);
  };

  f32x4 acc[4][4] = {};
  f16x8 afr[2][2], bfr0[2][2], bfr1[2][2];

  // prologue: 6 chunks in steady-state queue order
  stageB(0, 0, 2);             // B0(0)
  stageA(Aplane(0), 0, 0, 0);  // A0(0)
  stageA(Aplane(0), 0, 1, 1);  // A1(0)
  stageB(0, 1, 3);             // B1(0)
  stageB(1, 0, 6);             // B0(1)
  stageA(Aplane(1), 64, 0, 4); // A0(1)

  for (int k2 = 0; k2 < 32; ++k2) {
    const int ktb = k2 * 2;

    auto tile = [&](auto ec) {
      constexpr int E = decltype(ec)::v;
      const int kt = ktb + E;
      const int ktn = (kt + 1) & 63;    // wrap -> dummy restage, uniform counts
      const int ktn2 = (kt + 2) & 63;
      const f16* apn = Aplane(ktn);
      const f16* apn2 = Aplane(ktn2);
      const int kcoln = (ktn * 64) & 2047;
      const int kcoln2 = (ktn2 * 64) & 2047;
      const bool negA = top && (kt & 32);

      auto loadA = [&](int qm) {
        #pragma unroll
        for (int f = 0; f < 2; ++f)
          #pragma unroll
          for (int ks = 0; ks < 2; ++ks)
            afr[f][ks] = *(const f16x8*)(
                L + (E * 4 + wm) * 4096 + qm * 2048 + f * 1024 + arb + kofs[ks]);
        if (negA) {
          #pragma unroll
          for (int f = 0; f < 2; ++f) { afr[f][0] = -afr[f][0]; afr[f][1] = -afr[f][1]; }
        }
      };
      auto loadB = [&](f16x8 (&bq)[2][2], int qn) {
        #pragma unroll
        for (int fc = 0; fc < 2; ++fc)
          #pragma unroll
          for (int ks = 0; ks < 2; ++ks)
            bq[fc][ks] = *(const f16x8*)(
                L + (E * 4 + 2 + wn) * 4096 + qn * 2048 + fc * 1024 + arb + kofs[ks]);
      };
      auto mf16 = [&](f16x8 (&bq)[2][2], int accR, int accC) {
        __builtin_amdgcn_s_setprio(1);
        #pragma unroll
        for (int ks = 0; ks < 2; ++ks)     // ks OUTER: 4 independent per pass
          #pragma unroll
          for (int f = 0; f < 2; ++f)
            #pragma unroll
            for (int fc = 0; fc < 2; ++fc)
              acc[accR + f][accC + fc] = __builtin_amdgcn_mfma_f32_16x16x32_f16(
                  afr[f][ks], bq[fc][ks], acc[accR + f][accC + fc], 0, 0, 0);
        __builtin_amdgcn_s_setprio(0);
      };

      // gate: tile kt's 4 chunks visible; B0/A0(kt+1) stay in flight
      asm volatile("s_waitcnt vmcnt(4)" ::: "memory");
      __builtin_amdgcn_s_barrier();

      // P0: quadrant (0,0)
      loadA(0); loadB(bfr0, 0);
      stageA(apn, kcoln, 1, (E ^ 1) * 4 + 1);
      mf16(bfr0, 0, 0);

      // P1: quadrant (0,1)
      loadB(bfr1, 1);
      stageB(ktn, 1, (E ^ 1) * 4 + 3);
      mf16(bfr1, 0, 2);

      // P2: quadrant (1,1) -- mid-bar between ds-reads and depth-2 stages
      loadA(1);
      asm volatile("s_waitcnt lgkmcnt(0)" ::: "memory");
      __builtin_amdgcn_s_barrier();
      stageB(ktn2, 0, E * 4 + 2);
      mf16(bfr1, 2, 2);

      // P3: quadrant (1,0)
      stageA(apn2, kcoln2, 0, E * 4 + 0);
      mf16(bfr0, 2, 0);
    };

    tile(ic<0>{});
    tile(ic<1>{});
  }

  asm volatile("s_waitcnt vmcnt(0)" ::: "memory");

  // Epilogue: transposed write Q[j][n']; C/D map col=lane&15, row=(lane>>4)*4+r
  #pragma unroll
  for (int fc = 0; fc < 4; ++fc) {
    size_t j = (size_t)j0 + wn * 64 + fc * 16 + (lane & 15);
    #pragma unroll
    for (int fr = 0; fr < 4; ++fr) {
      int nn = n0 + wm * 64 + fr * 16 + ((lane >> 4) << 2);
      size_t off = j * 4096 + nn;
      f16x4 v;
      if (MODE == 1) {
        f16x4 o = *(const f16x4*)(Q + off);
        #pragma unroll
        for (int r = 0; r < 4; ++r)
          v[r] = (f16)(2.0f * acc[fr][fc][r] - (float)o[r]);
      } else {
        #pragma unroll
        for (int r = 0; r < 4; ++r)
          v[r] = (f16)acc[fr][fc][r];
      }
      *(f16x4*)(Q + off) = v;
    }
  }
}

// ---------------------------------------------------------------------------
// contract_k: out[b][n][t][o] (+)= sum_{tau,i} Re/Im( P_k[b,n,t-tau,i]*w[k,tau,i,o] )
// P combined plane: re at [j][n], im at [j][2048+n], row stride 4096.
// ---------------------------------------------------------------------------
template <bool CPLX>
__global__ __launch_bounds__(256, 4) void contract_k(
    const f16* __restrict__ Pc, const uint2* __restrict__ wpk,
    const float* __restrict__ biasr, const float* __restrict__ biasi,
    float* __restrict__ out, int k) {
  __shared__ __align__(16) uint32_t Plds[96 * 64];
  __shared__ __align__(16) uint32_t WA[96 * 32];
  __shared__ __align__(16) uint32_t WB[CPLX ? 96 * 32 : 32];

  const int t = threadIdx.x;
  const int n0 = blockIdx.x * 64;
  const int tt = blockIdx.y;
  const int b = blockIdx.z;

  #pragma unroll
  for (int it = 0; it < 3; ++it) {
    int task = it * 256 + t;
    int row = task >> 3, oc = task & 7;
    int tp = (tt - 2) * 32 + row;
    uint4 ur = {0, 0, 0, 0}, ui = {0, 0, 0, 0};
    if (tp >= 0) {
      size_t goff = ((size_t)b * 2048 + tp) * 4096 + n0 + oc * 8;
      ur = *(const uint4*)(Pc + goff);
      ui = *(const uint4*)(Pc + goff + 2048);
    }
    uint32_t* dst = &Plds[row * 64 + oc * 8];
    dst[0] = (ur.x & 0xffffu) | (ui.x << 16);
    dst[1] = (ur.x >> 16) | (ui.x & 0xffff0000u);
    dst[2] = (ur.y & 0xffffu) | (ui.y << 16);
    dst[3] = (ur.y >> 16) | (ui.y & 0xffff0000u);
    dst[4] = (ur.z & 0xffffu) | (ui.z << 16);
    dst[5] = (ur.z >> 16) | (ui.z & 0xffff0000u);
    dst[6] = (ur.w & 0xffffu) | (ui.w << 16);
    dst[7] = (ur.w >> 16) | (ui.w & 0xffff0000u);
  }
  #pragma unroll
  for (int it = 0; it < 12; ++it) {
    int idx = it * 256 + t;
    int q = idx >> 5, o = idx & 31;
    int tau = 2 - (q >> 5), ci = q & 31;
    uint2 wv = wpk[((k * TAUn + tau) * CIn + ci) * COn + o];
    WA[idx] = wv.x;
    if (CPLX) WB[idx] = wv.y;
  }
  __syncthreads();

  const int no = t & 7, ng = t >> 3;
  float aR[8] = {0, 0, 0, 0, 0, 0, 0, 0};
  float aI[8] = {0, 0, 0, 0, 0, 0, 0, 0};
  for (int q = 0; q < 96; ++q) {
    uint2 pp = *(const uint2*)&Plds[q * 64 + ng * 2];
    f16x2 h0 = __builtin_bit_cast(f16x2, pp.x);
    f16x2 h1 = __builtin_bit_cast(f16x2, pp.y);
    uint4 wa = *(const uint4*)&WA[q * 32 + no * 4];
    const uint32_t* wap = &wa.x;
    #pragma unroll
    for (int c = 0; c < 4; ++c) {
      f16x2 wv = __builtin_bit_cast(f16x2, wap[c]);
      aR[c] = fdot2(h0, wv, aR[c]);
      aR[4 + c] = fdot2(h1, wv, aR[4 + c]);
    }
    if (CPLX) {
      uint4 wb = *(const uint4*)&WB[q * 32 + no * 4];
      const uint32_t* wbp = &wb.x;
      #pragma unroll
      for (int c = 0; c < 4; ++c) {
        f16x2 wv = __builtin_bit_cast(f16x2, wbp[c]);
        aI[c] = fdot2(h0, wv, aI[c]);
        aI[4 + c] = fdot2(h1, wv, aI[4 + c]);
      }
    }
  }

  #pragma unroll
  for (int a = 0; a < 2; ++a) {
    size_t n = (size_t)n0 + ng * 2 + a;
    size_t ob = (((size_t)b * Nn + n) * Tn + tt) * COn + no * 4;
    if (!CPLX) {
      float4 v;
      v.x = aR[a * 4 + 0]; v.y = aR[a * 4 + 1];
      v.z = aR[a * 4 + 2]; v.w = aR[a * 4 + 3];
      float4 cur;
      if (k == 0) cur = *(const float4*)(biasr + no * 4);
      else cur = *(const float4*)(out + ob);
      v.x += cur.x; v.y += cur.y; v.z += cur.z; v.w += cur.w;
      *(float4*)(out + ob) = v;
    } else {
      float* po = out + ob * 2;
      float4 lo, hi;
      lo.x = aR[a * 4 + 0]; lo.y = aI[a * 4 + 0];
      lo.z = aR[a * 4 + 1]; lo.w = aI[a * 4 + 1];
      hi.x = aR[a * 4 + 2]; hi.y = aI[a * 4 + 2];
      hi.z = aR[a * 4 + 3]; hi.w = aI[a * 4 + 3];
      float4 c0, c1;
      if (k == 0) {
        const float* pr = biasr + no * 4;
        const float* pi = biasi + no * 4;
        c0 = make_float4(pr[0], pi[0], pr[1], pi[1]);
        c1 = make_float4(pr[2], pi[2], pr[3], pi[3]);
      } else {
        c0 = *(const float4*)(po);
        c1 = *(const float4*)(po + 4);
      }
      lo.x += c0.x; lo.y += c0.y; lo.z += c0.z; lo.w += c0.w;
      hi.x += c1.x; hi.y += c1.y; hi.z += c1.z; hi.w += c1.w;
      *(float4*)(po) = lo;
      *(float4*)(po + 4) = hi;
    }
  }
}

// ---------------------------------------------------------------------------
extern "C" void kernel_launch(void* const* d_in, const int* in_sizes, int n_in,
                              void* d_out, int out_size, void* d_ws, size_t ws_size,
                              hipStream_t stream) {
  (void)in_sizes; (void)n_in;
  const float* xr = (const float*)d_in[0];
  const float* xi = (const float*)d_in[1];
  const float* gr = (const float*)d_in[2];
  const float* gi = (const float*)d_in[3];
  const float* wr = (const float*)d_in[4];
  const float* wi = (const float*)d_in[5];
  const float* biasr = (const float*)d_in[6];
  const float* biasi = (const float*)d_in[7];
  float* out = (float*)d_out;

  const size_t PPLANE = (size_t)Jn * 4096 * sizeof(f16);  // 67,108,864 (combined)
  const size_t GPLANE = (size_t)Nn * Nn * sizeof(f16);    // 8,388,608
  const size_t WPK = (size_t)Kn * TAUn * CIn * COn * 8;   // 147,456
  if (ws_size < 2 * PPLANE + 2 * GPLANE + WPK) return;

  char* ws = (char*)d_ws;
  f16* P0 = (f16*)(ws);
  f16* P1 = (f16*)(ws + PPLANE);
  f16* Gr = (f16*)(ws + 2 * PPLANE);
  f16* Gi = (f16*)(ws + 2 * PPLANE + GPLANE);
  uint2* wpk = (uint2*)(ws + 2 * PPLANE + 2 * GPLANE);

  const bool cplx = (out_size == 2 * Bn * Nn * Tn * COn);

  pack_gso<<<dim3(4096), dim3(256), 0, stream>>>(gr, gi, Gr, Gi);
  pack_x<<<dim3(32, 32, 4), dim3(256), 0, stream>>>(xr, xi, P0);
  pack_w<<<dim3(72), dim3(256), 0, stream>>>(wr, wi, wpk);

  #define CONTRACT(KK, Pp)                                                         \
    do {                                                                           \
      if (cplx)                                                                    \
        contract_k<true><<<dim3(32, 64, 4), dim3(256), 0, stream>>>(               \
            Pp, wpk, biasr, biasi, out, KK);                                       \
      else                                                                         \
        contract_k<false><<<dim3(32, 64, 4), dim3(256), 0, stream>>>(              \
            Pp, wpk, biasr, biasi, out, KK);                                       \
    } while (0)

  CONTRACT(0, P0);
  cheb_gemm<0><<<dim3(2048), dim3(256), 65536, stream>>>(Gr, Gi, P0, P1);
  CONTRACT(1, P1);
  cheb_gemm<1><<<dim3(2048), dim3(256), 65536, stream>>>(Gr, Gi, P1, P0);
  CONTRACT(2, P0);
  cheb_gemm<1><<<dim3(2048), dim3(256), 65536, stream>>>(Gr, Gi, P0, P1);
  CONTRACT(3, P1);
  cheb_gemm<1><<<dim3(2048), dim3(256), 65536, stream>>>(Gr, Gi, P1, P0);
  CONTRACT(4, P0);
  cheb_gemm<1><<<dim3(2048), dim3(256), 65536, stream>>>(Gr, Gi, P0, P1);
  CONTRACT(5, P1);
  #undef CONTRACT
}

// Round 13
// 1891.265 us; speedup vs baseline: 1.1271x; 1.0258x over previous
//
#include <hip/hip_runtime.h>
#include <stdint.h>

// Problem constants (ComplexChebTemporalConv)
#define Bn 4
#define Nn 2048
#define Tn 64
#define CIn 32
#define COn 32
#define Kn 6
#define TAUn 3
#define Jn 8192  // B*T*CI

typedef _Float16 f16;
typedef _Float16 f16x2 __attribute__((ext_vector_type(2)));
typedef _Float16 f16x4 __attribute__((ext_vector_type(4)));
typedef _Float16 f16x8 __attribute__((ext_vector_type(8)));
typedef float f32x4 __attribute__((ext_vector_type(4)));

template <int N> struct ic { static constexpr int v = N; };

#if defined(__has_builtin)
#if __has_builtin(__builtin_amdgcn_fdot2)
#define HAVE_FDOT2 1
#endif
#endif

__device__ __forceinline__ float fdot2(f16x2 a, f16x2 b, float c) {
#ifdef HAVE_FDOT2
  return __builtin_amdgcn_fdot2(a, b, c, false);
#else
  return c + (float)a[0] * (float)b[0] + (float)a[1] * (float)b[1];
#endif
}

__device__ __forceinline__ void gld_lds16(const void* g, void* l) {
  auto gp = (const __attribute__((address_space(1))) uint32_t*)(uintptr_t)g;
  auto lp = (__attribute__((address_space(3))) uint32_t*)(uint32_t)(uintptr_t)l;
  __builtin_amdgcn_global_load_lds(gp, lp, 16, 0, 0);
}

// ---------------------------------------------------------------------------
// pack_gso: fp32 gso planes -> f16 planes (row-major [n][m])
// ---------------------------------------------------------------------------
__global__ __launch_bounds__(256) void pack_gso(const float* __restrict__ gr,
                                                const float* __restrict__ gi,
                                                f16* __restrict__ Gr,
                                                f16* __restrict__ Gi) {
  int u = blockIdx.x * 256 + threadIdx.x;
  float4 vr = ((const float4*)gr)[u];
  float4 vi = ((const float4*)gi)[u];
  f16x4 hr, hi;
  hr[0] = (f16)vr.x; hr[1] = (f16)vr.y; hr[2] = (f16)vr.z; hr[3] = (f16)vr.w;
  hi[0] = (f16)vi.x; hi[1] = (f16)vi.y; hi[2] = (f16)vi.z; hi[3] = (f16)vi.w;
  ((f16x4*)Gr)[u] = hr;
  ((f16x4*)Gi)[u] = hi;
}

// ---------------------------------------------------------------------------
// pack_x: x [b][n][q] fp32 -> combined P0[j=b*2048+q][4096]: re at col n, im at 2048+n
// ---------------------------------------------------------------------------
__global__ __launch_bounds__(256) void pack_x(const float* __restrict__ xr,
                                              const float* __restrict__ xi,
                                              f16* __restrict__ P0) {
  __shared__ float tile[64][65];
  const int t = threadIdx.x;
  const int q0 = blockIdx.x * 64;
  const int n0 = blockIdx.y * 64;
  const int b = blockIdx.z;
  const int rr = t >> 4;
  const int cc = (t & 15) * 4;
  #pragma unroll
  for (int plane = 0; plane < 2; ++plane) {
    const float* src = plane ? xi : xr;
    if (plane) __syncthreads();
    #pragma unroll
    for (int it = 0; it < 4; ++it) {
      int n = it * 16 + rr;
      float4 v = *(const float4*)(src + ((size_t)b * Nn + n0 + n) * 2048 + q0 + cc);
      tile[n][cc + 0] = v.x; tile[n][cc + 1] = v.y;
      tile[n][cc + 2] = v.z; tile[n][cc + 3] = v.w;
    }
    __syncthreads();
    #pragma unroll
    for (int it = 0; it < 4; ++it) {
      int q = it * 16 + rr;
      f16x4 hv;
      hv[0] = (f16)tile[cc + 0][q];
      hv[1] = (f16)tile[cc + 1][q];
      hv[2] = (f16)tile[cc + 2][q];
      hv[3] = (f16)tile[cc + 3][q];
      *(f16x4*)(P0 + ((size_t)b * 2048 + q0 + q) * 4096 + plane * 2048 + n0 + cc) = hv;
    }
  }
}

// ---------------------------------------------------------------------------
// pack_w: wpk[idx].x = (wr, -wi), wpk[idx].y = (wi, wr); idx = [k][tau][ci][co]
// ---------------------------------------------------------------------------
__global__ __launch_bounds__(256) void pack_w(const float* __restrict__ wr,
                                              const float* __restrict__ wi,
                                              uint2* __restrict__ wpk) {
  int idx = blockIdx.x * 256 + threadIdx.x;
  if (idx >= Kn * TAUn * CIn * COn) return;
  float r = wr[idx], i = wi[idx];
  uint16_t hr = __builtin_bit_cast(uint16_t, (f16)r);
  uint16_t hi = __builtin_bit_cast(uint16_t, (f16)i);
  uint16_t hni = __builtin_bit_cast(uint16_t, (f16)(-i));
  uint2 o;
  o.x = (uint32_t)hr | ((uint32_t)hni << 16);
  o.y = (uint32_t)hi | ((uint32_t)hr << 16);
  wpk[idx] = o;
}

// ---------------------------------------------------------------------------
// cheb_gemm r12 (UNCHANGED in r13) = r11 kernel + SQUARE co-residency swizzle.
//   256 thr = 4 waves (2M x 2N); tile 128(n') x 128(j), BK=64, wave 64x64.
//   LDS 64 KB: 8 x 8KB chunks; 2 blocks/CU (block-level TLP).
// Swizzle: 64 co-resident blocks per XCD form an 8x8 (bn x bj) square:
//   s = l&63, wv = l>>6; bj = xcd*8 + (s>>3); bn = (s&7) + 8*wv.
//   Window footprint 16 MB (FETCH-proven: 1.10 GB -> 411 MB, r12).
// Staging COALESCED + XOR-SWIZZLED (r11-proven): LDS linear; global src
//   carries swizzle cg = (tid&7)^(trow&7); frag reads un-swizzle.
// Schedule per K-tile (r10-proven, 2 barriers): gate vmcnt(4)+bar;
//   P0{loadA(0),loadB0,stage A1(kt+1),mfma}; P1{loadB1,stage B1(kt+1),mfma};
//   P2{loadA(1),lgkmcnt(0)+bar,stage B0(kt+2),mfma}; P3{stage A0(kt+2),mfma}.
//   C[n'][j] = sum G2[n'][k'] P[j][k'];  G2 = [[Gr,-Gi],[Gi,Gr]].
// MODE 0: Q = C ; MODE 1: Q = 2C - Q (in place).
// ---------------------------------------------------------------------------
template <int MODE>
__global__ __launch_bounds__(256, 2) void cheb_gemm(
    const f16* __restrict__ Gr, const f16* __restrict__ Gi,
    const f16* __restrict__ P, f16* __restrict__ Q) {
  extern __shared__ __align__(16) char lds[];
  f16* L = (f16*)lds;

  const int tid = threadIdx.x;
  const int lane = tid & 63;
  const int w = tid >> 6;
  const int wm = w >> 1;              // 0..1 : 64-row n'-strip
  const int wn = w & 1;               // 0..1 : 64-row j-strip
  const int sub = lane >> 4, rr = lane & 15;

  const int bid = blockIdx.x;
  const int xcd = bid & 7;
  const int l = bid >> 3;             // 0..255 in-XCD
  const int s = l & 63, wv = l >> 6;  // window pos / window idx
  const int bj = xcd * 8 + (s >> 3);  // 0..63
  const int bn = (s & 7) + 8 * wv;    // 0..31
  const int n0 = bn * 128, j0 = bj * 128;
  const bool top = n0 < 2048;
  const int gmbase = n0 & 2047;

  // ---- staging invariants (coalesced, global-side swizzle) ----
  const int trow = tid >> 3;                       // 0..31
  const int cg = (tid & 7) ^ (trow & 7);           // swizzled 16B k-chunk
  const size_t aoffg = (size_t)(gmbase + trow) * 2048 + cg * 8;
  const size_t boffg = (size_t)(j0 + trow) * 4096 + cg * 8;
  const int sdst = w * 512;                        // + p*2048 + slot*4096 (elems)

  // ---- frag-read invariants (un-swizzle) ----
  const int arb = rr * 64 + (sub ^ (rr & 3)) * 8;  // + qX*2048 + f*1024 + kofs
  const int x32 = ((rr >> 2) & 1) * 32;
  const int kofs[2] = {x32, 32 - x32};             // (ks ^ xb)*32

  auto stageA = [&](const f16* plane, int kcol, int h, int slot) {
    #pragma unroll
    for (int p = 0; p < 2; ++p)
      gld_lds16(plane + aoffg + h * 131072 + p * 65536 + kcol,
                L + slot * 4096 + sdst + p * 2048);
  };
  auto stageB = [&](int kt_, int h, int slot) {
    #pragma unroll
    for (int p = 0; p < 2; ++p)
      gld_lds16(P + boffg + h * 262144 + p * 131072 + kt_ * 64,
                L + slot * 4096 + sdst + p * 2048);
  };
  auto Aplane = [&](int kt_) -> const f16* {
    bool kr = (kt_ & 32) != 0;  // k' >= 2048
    return top ? (kr ? Gi : Gr) : (kr ? Gr : Gi);
  };

  f32x4 acc[4][4] = {};
  f16x8 afr[2][2], bfr0[2][2], bfr1[2][2];

  // prologue: 6 chunks in steady-state queue order
  stageB(0, 0, 2);             // B0(0)
  stageA(Aplane(0), 0, 0, 0);  // A0(0)
  stageA(Aplane(0), 0, 1, 1);  // A1(0)
  stageB(0, 1, 3);             // B1(0)
  stageB(1, 0, 6);             // B0(1)
  stageA(Aplane(1), 64, 0, 4); // A0(1)

  for (int k2 = 0; k2 < 32; ++k2) {
    const int ktb = k2 * 2;

    auto tile = [&](auto ec) {
      constexpr int E = decltype(ec)::v;
      const int kt = ktb + E;
      const int ktn = (kt + 1) & 63;    // wrap -> dummy restage, uniform counts
      const int ktn2 = (kt + 2) & 63;
      const f16* apn = Aplane(ktn);
      const f16* apn2 = Aplane(ktn2);
      const int kcoln = (ktn * 64) & 2047;
      const int kcoln2 = (ktn2 * 64) & 2047;
      const bool negA = top && (kt & 32);

      auto loadA = [&](int qm) {
        #pragma unroll
        for (int f = 0; f < 2; ++f)
          #pragma unroll
          for (int ks = 0; ks < 2; ++ks)
            afr[f][ks] = *(const f16x8*)(
                L + (E * 4 + wm) * 4096 + qm * 2048 + f * 1024 + arb + kofs[ks]);
        if (negA) {
          #pragma unroll
          for (int f = 0; f < 2; ++f) { afr[f][0] = -afr[f][0]; afr[f][1] = -afr[f][1]; }
        }
      };
      auto loadB = [&](f16x8 (&bq)[2][2], int qn) {
        #pragma unroll
        for (int fc = 0; fc < 2; ++fc)
          #pragma unroll
          for (int ks = 0; ks < 2; ++ks)
            bq[fc][ks] = *(const f16x8*)(
                L + (E * 4 + 2 + wn) * 4096 + qn * 2048 + fc * 1024 + arb + kofs[ks]);
      };
      auto mf16 = [&](f16x8 (&bq)[2][2], int accR, int accC) {
        __builtin_amdgcn_s_setprio(1);
        #pragma unroll
        for (int ks = 0; ks < 2; ++ks)     // ks OUTER: 4 independent per pass
          #pragma unroll
          for (int f = 0; f < 2; ++f)
            #pragma unroll
            for (int fc = 0; fc < 2; ++fc)
              acc[accR + f][accC + fc] = __builtin_amdgcn_mfma_f32_16x16x32_f16(
                  afr[f][ks], bq[fc][ks], acc[accR + f][accC + fc], 0, 0, 0);
        __builtin_amdgcn_s_setprio(0);
      };

      // gate: tile kt's 4 chunks visible; B0/A0(kt+1) stay in flight
      asm volatile("s_waitcnt vmcnt(4)" ::: "memory");
      __builtin_amdgcn_s_barrier();

      // P0: quadrant (0,0)
      loadA(0); loadB(bfr0, 0);
      stageA(apn, kcoln, 1, (E ^ 1) * 4 + 1);
      mf16(bfr0, 0, 0);

      // P1: quadrant (0,1)
      loadB(bfr1, 1);
      stageB(ktn, 1, (E ^ 1) * 4 + 3);
      mf16(bfr1, 0, 2);

      // P2: quadrant (1,1) -- mid-bar between ds-reads and depth-2 stages
      loadA(1);
      asm volatile("s_waitcnt lgkmcnt(0)" ::: "memory");
      __builtin_amdgcn_s_barrier();
      stageB(ktn2, 0, E * 4 + 2);
      mf16(bfr1, 2, 2);

      // P3: quadrant (1,0)
      stageA(apn2, kcoln2, 0, E * 4 + 0);
      mf16(bfr0, 2, 0);
    };

    tile(ic<0>{});
    tile(ic<1>{});
  }

  asm volatile("s_waitcnt vmcnt(0)" ::: "memory");

  // Epilogue: transposed write Q[j][n']; C/D map col=lane&15, row=(lane>>4)*4+r
  #pragma unroll
  for (int fc = 0; fc < 4; ++fc) {
    size_t j = (size_t)j0 + wn * 64 + fc * 16 + (lane & 15);
    #pragma unroll
    for (int fr = 0; fr < 4; ++fr) {
      int nn = n0 + wm * 64 + fr * 16 + ((lane >> 4) << 2);
      size_t off = j * 4096 + nn;
      f16x4 v;
      if (MODE == 1) {
        f16x4 o = *(const f16x4*)(Q + off);
        #pragma unroll
        for (int r = 0; r < 4; ++r)
          v[r] = (f16)(2.0f * acc[fr][fc][r] - (float)o[r]);
      } else {
        #pragma unroll
        for (int r = 0; r < 4; ++r)
          v[r] = (f16)acc[fr][fc][r];
      }
      *(f16x4*)(Q + off) = v;
    }
  }
}

// ---------------------------------------------------------------------------
// contract_k r13: T-BLOCKED x4. Each block handles 4 consecutive t values:
//   stages rows (t0-2)*32 .. (t0+3)*32+31 = 192 rows (48KB) instead of
//   4 x 96 = 384 -> P-plane traffic HALVED per contract. Weight read per q
//   hoisted across the 4 t-subs (LDS bytes per fdot2 down 2.7x).
// Row mapping: output tt = t0+ts uses LDS row ts*32 + q (q 0..95);
//   weight row q <-> P row q unchanged (tau = 2-(q>>5)).
// Grid (32 n-chunks, 16 t-groups, 4 b), 256 thr; LDS 60/72 KB -> 2 blocks/CU.
// out[b][n][t][o] (+)= sum_{tau,i} Re/Im( P_k[b,n,t-tau,i]*w[k,tau,i,o] );
// k==0 initializes with bias. P combined plane: re [j][n], im [j][2048+n].
// ---------------------------------------------------------------------------
template <bool CPLX>
__global__ __launch_bounds__(256, 2) void contract_k(
    const f16* __restrict__ Pc, const uint2* __restrict__ wpk,
    const float* __restrict__ biasr, const float* __restrict__ biasi,
    float* __restrict__ out, int k) {
  __shared__ __align__(16) uint32_t Plds[192 * 64];          // 48KB (pr,pi) half2
  __shared__ __align__(16) uint32_t WA[96 * 32];             // 12KB (wr,-wi)
  __shared__ __align__(16) uint32_t WB[CPLX ? 96 * 32 : 32]; // 12KB (wi, wr)

  const int t = threadIdx.x;
  const int n0 = blockIdx.x * 64;
  const int t0 = blockIdx.y * 4;
  const int b = blockIdx.z;

  #pragma unroll
  for (int it = 0; it < 6; ++it) {
    int task = it * 256 + t;           // 1536 tasks: 192 rows x 8 octets
    int row = task >> 3, oc = task & 7;
    int tp = (t0 - 2) * 32 + row;      // global j offset within this b
    uint4 ur = {0, 0, 0, 0}, ui = {0, 0, 0, 0};
    if (tp >= 0) {
      size_t goff = ((size_t)b * 2048 + tp) * 4096 + n0 + oc * 8;
      ur = *(const uint4*)(Pc + goff);
      ui = *(const uint4*)(Pc + goff + 2048);
    }
    uint32_t* dst = &Plds[row * 64 + oc * 8];
    dst[0] = (ur.x & 0xffffu) | (ui.x << 16);
    dst[1] = (ur.x >> 16) | (ui.x & 0xffff0000u);
    dst[2] = (ur.y & 0xffffu) | (ui.y << 16);
    dst[3] = (ur.y >> 16) | (ui.y & 0xffff0000u);
    dst[4] = (ur.z & 0xffffu) | (ui.z << 16);
    dst[5] = (ur.z >> 16) | (ui.z & 0xffff0000u);
    dst[6] = (ur.w & 0xffffu) | (ui.w << 16);
    dst[7] = (ur.w >> 16) | (ui.w & 0xffff0000u);
  }
  #pragma unroll
  for (int it = 0; it < 12; ++it) {
    int idx = it * 256 + t;            // q*32+o; tau = 2 - (q>>5)
    int q = idx >> 5, o = idx & 31;
    int tau = 2 - (q >> 5), ci = q & 31;
    uint2 wv = wpk[((k * TAUn + tau) * CIn + ci) * COn + o];
    WA[idx] = wv.x;
    if (CPLX) WB[idx] = wv.y;
  }
  __syncthreads();

  const int no = t & 7, ng = t >> 3;   // o-quad, n-pair group
  float aR[4][8] = {};
  float aI[4][8] = {};
  for (int q = 0; q < 96; ++q) {
    uint4 wa = *(const uint4*)&WA[q * 32 + no * 4];
    const uint32_t* wap = &wa.x;
    uint4 wb;
    const uint32_t* wbp = &wb.x;
    if (CPLX) wb = *(const uint4*)&WB[q * 32 + no * 4];
    #pragma unroll
    for (int ts = 0; ts < 4; ++ts) {
      uint2 pp = *(const uint2*)&Plds[(ts * 32 + q) * 64 + ng * 2];
      f16x2 h0 = __builtin_bit_cast(f16x2, pp.x);
      f16x2 h1 = __builtin_bit_cast(f16x2, pp.y);
      #pragma unroll
      for (int c = 0; c < 4; ++c) {
        f16x2 wv = __builtin_bit_cast(f16x2, wap[c]);
        aR[ts][c] = fdot2(h0, wv, aR[ts][c]);
        aR[ts][4 + c] = fdot2(h1, wv, aR[ts][4 + c]);
      }
      if (CPLX) {
        #pragma unroll
        for (int c = 0; c < 4; ++c) {
          f16x2 wv = __builtin_bit_cast(f16x2, wbp[c]);
          aI[ts][c] = fdot2(h0, wv, aI[ts][c]);
          aI[ts][4 + c] = fdot2(h1, wv, aI[ts][4 + c]);
        }
      }
    }
  }

  #pragma unroll
  for (int ts = 0; ts < 4; ++ts) {
    const int tt = t0 + ts;
    #pragma unroll
    for (int a = 0; a < 2; ++a) {
      size_t n = (size_t)n0 + ng * 2 + a;
      size_t ob = (((size_t)b * Nn + n) * Tn + tt) * COn + no * 4;
      if (!CPLX) {
        float4 v;
        v.x = aR[ts][a * 4 + 0]; v.y = aR[ts][a * 4 + 1];
        v.z = aR[ts][a * 4 + 2]; v.w = aR[ts][a * 4 + 3];
        float4 cur;
        if (k == 0) cur = *(const float4*)(biasr + no * 4);
        else cur = *(const float4*)(out + ob);
        v.x += cur.x; v.y += cur.y; v.z += cur.z; v.w += cur.w;
        *(float4*)(out + ob) = v;
      } else {
        float* po = out + ob * 2;
        float4 lo, hi;
        lo.x = aR[ts][a * 4 + 0]; lo.y = aI[ts][a * 4 + 0];
        lo.z = aR[ts][a * 4 + 1]; lo.w = aI[ts][a * 4 + 1];
        hi.x = aR[ts][a * 4 + 2]; hi.y = aI[ts][a * 4 + 2];
        hi.z = aR[ts][a * 4 + 3]; hi.w = aI[ts][a * 4 + 3];
        float4 c0, c1;
        if (k == 0) {
          const float* pr = biasr + no * 4;
          const float* pi = biasi + no * 4;
          c0 = make_float4(pr[0], pi[0], pr[1], pi[1]);
          c1 = make_float4(pr[2], pi[2], pr[3], pi[3]);
        } else {
          c0 = *(const float4*)(po);
          c1 = *(const float4*)(po + 4);
        }
        lo.x += c0.x; lo.y += c0.y; lo.z += c0.z; lo.w += c0.w;
        hi.x += c1.x; hi.y += c1.y; hi.z += c1.z; hi.w += c1.w;
        *(float4*)(po) = lo;
        *(float4*)(po + 4) = hi;
      }
    }
  }
}

// ---------------------------------------------------------------------------
extern "C" void kernel_launch(void* const* d_in, const int* in_sizes, int n_in,
                              void* d_out, int out_size, void* d_ws, size_t ws_size,
                              hipStream_t stream) {
  (void)in_sizes; (void)n_in;
  const float* xr = (const float*)d_in[0];
  const float* xi = (const float*)d_in[1];
  const float* gr = (const float*)d_in[2];
  const float* gi = (const float*)d_in[3];
  const float* wr = (const float*)d_in[4];
  const float* wi = (const float*)d_in[5];
  const float* biasr = (const float*)d_in[6];
  const float* biasi = (const float*)d_in[7];
  float* out = (float*)d_out;

  const size_t PPLANE = (size_t)Jn * 4096 * sizeof(f16);  // 67,108,864 (combined)
  const size_t GPLANE = (size_t)Nn * Nn * sizeof(f16);    // 8,388,608
  const size_t WPK = (size_t)Kn * TAUn * CIn * COn * 8;   // 147,456
  if (ws_size < 2 * PPLANE + 2 * GPLANE + WPK) return;

  char* ws = (char*)d_ws;
  f16* P0 = (f16*)(ws);
  f16* P1 = (f16*)(ws + PPLANE);
  f16* Gr = (f16*)(ws + 2 * PPLANE);
  f16* Gi = (f16*)(ws + 2 * PPLANE + GPLANE);
  uint2* wpk = (uint2*)(ws + 2 * PPLANE + 2 * GPLANE);

  const bool cplx = (out_size == 2 * Bn * Nn * Tn * COn);

  pack_gso<<<dim3(4096), dim3(256), 0, stream>>>(gr, gi, Gr, Gi);
  pack_x<<<dim3(32, 32, 4), dim3(256), 0, stream>>>(xr, xi, P0);
  pack_w<<<dim3(72), dim3(256), 0, stream>>>(wr, wi, wpk);

  #define CONTRACT(KK, Pp)                                                         \
    do {                                                                           \
      if (cplx)                                                                    \
        contract_k<true><<<dim3(32, 16, 4), dim3(256), 0, stream>>>(               \
            Pp, wpk, biasr, biasi, out, KK);                                       \
      else                                                                         \
        contract_k<false><<<dim3(32, 16, 4), dim3(256), 0, stream>>>(              \
            Pp, wpk, biasr, biasi, out, KK);                                       \
    } while (0)

  CONTRACT(0, P0);
  cheb_gemm<0><<<dim3(2048), dim3(256), 65536, stream>>>(Gr, Gi, P0, P1);
  CONTRACT(1, P1);
  cheb_gemm<1><<<dim3(2048), dim3(256), 65536, stream>>>(Gr, Gi, P1, P0);
  CONTRACT(2, P0);
  cheb_gemm<1><<<dim3(2048), dim3(256), 65536, stream>>>(Gr, Gi, P0, P1);
  CONTRACT(3, P1);
  cheb_gemm<1><<<dim3(2048), dim3(256), 65536, stream>>>(Gr, Gi, P1, P0);
  CONTRACT(4, P0);
  cheb_gemm<1><<<dim3(2048), dim3(256), 65536, stream>>>(Gr, Gi, P0, P1);
  CONTRACT(5, P1);
  #undef CONTRACT
}